// Round 9
// baseline (279.616 us; speedup 1.0000x reference)
//
#include <hip/hip_runtime.h>

// QuantizerEncoder: code[n,h,w,m] = argmax_k < wq[m] @ q_raw[n,h,w,m], wk[m] @ cb[m,k] >
// n=16, d=512, h=64, w=64, m=4, kcodes=256, dm=128
//
// Round 14: argmax wave re-split 4 code-groups x 2 pixel-halves (was 8 code-groups x
// all pixels). B-fragments are IDENTICAL across waves owning different codes -> old
// layout read each LDS tile 8x; new layout halves B-read traffic (8 vs 16
// ds_read_b128/wave/row) and narrows the merge 8->4 partials. MFMA count invariant.
// Register fit (R8 lesson, (512,4) cap=128): Af 64 + pf 16 + streamed Bf 4 + acc 16
// + addr/scan ~18 = ~118. Enablers: (a) Bf streamed one-at-a-time into 4 MFMAs;
// (b) LDS write of row r+1 moved to TOP of row r (barrier at end of r-1 already
// fenced that buffer's readers) so pf/cv die before compute; single pf buffer,
// 1-row slack (R13 proved depth>1 is null). Also: wl_cnt zeroing folded into
// a_kernel block 0 (memset dispatch dropped). R13 macro pipeline reverted.

#define MM   4
#define KC   256
#define DM   128
#define HW   4096   // h*w
#define WW_  64
#define EPS  0.045f
#define WLC  16384  // per-m worklist capacity
#define RPB  4      // pixels per rescue sweep
#define RSH  136    // LDS row stride in halfs (272B, 16B-aligned, conflict-free b128)

typedef _Float16 f16x8 __attribute__((ext_vector_type(8)));
typedef _Float16 f16x4 __attribute__((ext_vector_type(4)));
typedef _Float16 f16x2 __attribute__((ext_vector_type(2)));
typedef float    f32x4 __attribute__((ext_vector_type(4)));
typedef float    f32x2 __attribute__((ext_vector_type(2)));

// ---- Kernel 1: A[m][e][d] = sum_c wk[m][c][e] * wq[m][c][d]  (fp64); also zeroes wl_cnt ----
__global__ __launch_bounds__(128) void a_kernel(const float* __restrict__ wk,
                                                const float* __restrict__ wq,
                                                double* __restrict__ A,
                                                int* __restrict__ wl_cnt) {
    if (blockIdx.x == 0 && threadIdx.x < 64) wl_cnt[threadIdx.x] = 0;
    int me = blockIdx.x;           // m*128 + e
    int d  = threadIdx.x;
    int m  = me >> 7;
    int e  = me & 127;
    const float* wkm = wk + (size_t)m * DM * DM + e;       // wk[m][c][e], stride DM
    const float* wqm = wq + (size_t)m * DM * DM + d;       // wq[m][c][d], stride DM
    double s0 = 0.0, s1 = 0.0, s2 = 0.0, s3 = 0.0;
#pragma unroll 8
    for (int c = 0; c < DM; c += 4) {
        s0 = fma((double)wkm[(size_t)(c+0) * DM], (double)wqm[(size_t)(c+0) * DM], s0);
        s1 = fma((double)wkm[(size_t)(c+1) * DM], (double)wqm[(size_t)(c+1) * DM], s1);
        s2 = fma((double)wkm[(size_t)(c+2) * DM], (double)wqm[(size_t)(c+2) * DM], s2);
        s3 = fma((double)wkm[(size_t)(c+3) * DM], (double)wqm[(size_t)(c+3) * DM], s3);
    }
    A[(size_t)me * DM + d] = (s0 + s1) + (s2 + s3);
}

// ---- Kernel 2: keff[m][k][d] = sum_e cb[m][k][e]*A[m][e][d]; store fp16 + fp64-transposed ----
__global__ __launch_bounds__(128) void keff_kernel(const float* __restrict__ cb,
                                                   const double* __restrict__ A,
                                                   double* __restrict__ keffdT,
                                                   _Float16* __restrict__ keff16) {
    int mk = blockIdx.x;           // m*256 + k
    int d  = threadIdx.x;
    int m  = mk >> 8;
    int k  = mk & 255;
    const float*  cbr = cb + (size_t)mk * DM;              // cb[m][k][*]
    const double* Am  = A + (size_t)m * DM * DM + d;       // A[m][e][d], stride DM
    double s0 = 0.0, s1 = 0.0, s2 = 0.0, s3 = 0.0;
#pragma unroll 8
    for (int e = 0; e < DM; e += 4) {
        s0 = fma((double)cbr[e+0], Am[(size_t)(e+0) * DM], s0);
        s1 = fma((double)cbr[e+1], Am[(size_t)(e+1) * DM], s1);
        s2 = fma((double)cbr[e+2], Am[(size_t)(e+2) * DM], s2);
        s3 = fma((double)cbr[e+3], Am[(size_t)(e+3) * DM], s3);
    }
    double s = (s0 + s1) + (s2 + s3);
    keffdT[((size_t)m * DM + d) * KC + k] = s;             // transposed: rescue reads coalesced
    keff16[(size_t)mk * DM + d] = (_Float16)s;
}

// ---- Kernel 3: MFMA argmax, 8 waves = 4 code-groups x 2 pixel-halves, 512 blocks ----
__global__ __launch_bounds__(512, 4) void argmax_mfma(const float* __restrict__ latent,
                                                      const _Float16* __restrict__ keff16,
                                                      int* __restrict__ out,
                                                      int* __restrict__ wl_cnt,
                                                      int* __restrict__ wl) {
    __shared__ _Float16 lq[2][64 * RSH];   // 2 x 17,408 B q tiles
    __shared__ float pbv[2][64][4];        // double-buffered partials, 4 code-group slots
    __shared__ float psv[2][64][4];
    __shared__ int   pbi[2][64][4];

    int blk  = blockIdx.x;          // 0..511 = n(16) x m(4) x hg(8)
    int n    = blk >> 5;
    int m    = (blk >> 3) & 3;
    int hg   = blk & 7;
    int tid  = threadIdx.x;
    int wave = tid >> 6;            // 0..7
    int lane = tid & 63;
    int col  = lane & 15;
    int quad = lane >> 4;
    int cg   = wave >> 1;           // code group 0..3 (64 codes each)
    int ph   = wave & 1;            // pixel half 0..1 (32 pixels each)
    int w2   = (tid & 31) * 2;      // staging: pixel base (2 pixels/thread)
    int db   = (tid >> 5) * 8;      // staging: d-plane base (16 groups x 8 = 128)

    // ---- A-frags: this wave's 64 codes [cg*64, cg*64+64), 64 VGPRs ----
    f16x8 Af[4][4];
    {
        const _Float16* kbase = keff16 + ((size_t)m * KC + cg * 64) * DM;
#pragma unroll
        for (int t = 0; t < 4; ++t)
#pragma unroll
            for (int s = 0; s < 4; ++s)
                Af[t][s] = *(const f16x8*)(kbase + (size_t)(t * 16 + col) * DM + s * 32 + quad * 8);
    }

    const float* lp0 = latent + ((size_t)(n * 512 + m * DM)) * HW + (size_t)(hg * 8) * WW_;

    // ---- prologue: stage row 0 direct; issue pf <- row 1 ----
    f32x2 pf[8];
    {
        f32x2 p0[8];
#pragma unroll
        for (int pp = 0; pp < 8; ++pp)
            p0[pp] = *(const f32x2*)(lp0 + (size_t)(db + pp) * HW + w2);
#pragma unroll
        for (int j = 0; j < 2; ++j) {
            f16x8 v;
#pragma unroll
            for (int pp = 0; pp < 8; ++pp) v[pp] = (_Float16)p0[pp][j];
            *(f16x8*)&lq[0][(size_t)(w2 + j) * RSH + db] = v;
        }
    }
    {
        const float* lp_ = lp0 + (size_t)1 * WW_;
#pragma unroll
        for (int pp = 0; pp < 8; ++pp)
            pf[pp] = *(const f32x2*)(lp_ + (size_t)(db + pp) * HW + w2);
    }
    __syncthreads();

    for (int r = 0; r < 8; ++r) {
        int cur = r & 1;

        // ---- TOP: convert pf (row r+1) -> write lq[cur^1]; then reissue pf <- row r+2 ----
        // Legal: barrier at end of row r-1 fenced all readers of lq[cur^1].
        if (r < 7) {
            f16x8 cv0, cv1;
#pragma unroll
            for (int pp = 0; pp < 8; ++pp) { cv0[pp] = (_Float16)pf[pp][0];
                                             cv1[pp] = (_Float16)pf[pp][1]; }
            *(f16x8*)&lq[cur ^ 1][(size_t)(w2 + 0) * RSH + db] = cv0;
            *(f16x8*)&lq[cur ^ 1][(size_t)(w2 + 1) * RSH + db] = cv1;
        }
        if (r < 6) {
            const float* lp_ = lp0 + (size_t)(r + 2) * WW_;
#pragma unroll
            for (int pp = 0; pp < 8; ++pp)
                pf[pp] = *(const f32x2*)(lp_ + (size_t)(db + pp) * HW + w2);
        }

        // ---- compute: 2 pixel-tiles (this wave's half), streamed Bf, acc[4] code-tiles ----
#pragma unroll
        for (int pl = 0; pl < 2; ++pl) {
            int p = ph * 2 + pl;
            f32x4 acc[4];
#pragma unroll
            for (int t = 0; t < 4; ++t) acc[t] = (f32x4){0.f, 0.f, 0.f, 0.f};
#pragma unroll
            for (int s = 0; s < 4; ++s) {
                f16x8 Bf = *(const f16x8*)&lq[cur][(size_t)(p * 16 + col) * RSH + s * 32 + quad * 8];
                acc[0] = __builtin_amdgcn_mfma_f32_16x16x32_f16(Af[0][s], Bf, acc[0], 0, 0, 0);
                acc[1] = __builtin_amdgcn_mfma_f32_16x16x32_f16(Af[1][s], Bf, acc[1], 0, 0, 0);
                acc[2] = __builtin_amdgcn_mfma_f32_16x16x32_f16(Af[2][s], Bf, acc[2], 0, 0, 0);
                acc[3] = __builtin_amdgcn_mfma_f32_16x16x32_f16(Af[3][s], Bf, acc[3], 0, 0, 0);
            }
            // scan 16 values: idx = cg*64 + t*16 + quad*4 + g, ascending in (t,g)
            float bv = acc[0][0];
            int   bi = cg * 64 + quad * 4;
            float sv = -3.0e38f;
#pragma unroll
            for (int t = 0; t < 4; ++t)
#pragma unroll
                for (int g = 0; g < 4; ++g) {
                    if (t == 0 && g == 0) continue;
                    float v   = acc[t][g];
                    int   idx = cg * 64 + t * 16 + quad * 4 + g;
                    if (v > bv)      { sv = bv; bv = v; bi = idx; }
                    else if (v > sv) sv = v;
                }
            // merge across the 4 quads holding this pixel
#pragma unroll
            for (int off = 16; off < 64; off <<= 1) {
                float ov = __shfl_xor(bv, off);
                int   oi = __shfl_xor(bi, off);
                float os = __shfl_xor(sv, off);
                bool  take  = (ov > bv) || (ov == bv && oi < bi);
                float loser = take ? bv : ov;
                sv = fmaxf(fmaxf(sv, os), loser);
                if (take) { bv = ov; bi = oi; }
            }
            if (quad == 0) {
                int P = p * 16 + col;
                pbv[cur][P][cg] = bv; psv[cur][P][cg] = sv; pbi[cur][P][cg] = bi;
            }
        }
        __syncthreads();   // partials[cur] published (lq[cur^1] was written at TOP)

        // ---- merge: 256 threads, pixel P=tid>>2, slot=tid&3, 2 shfl steps ----
        if (tid < 256) {
            int P    = tid >> 2;
            int slot = tid & 3;
            float bv = pbv[cur][P][slot];
            float sv = psv[cur][P][slot];
            int   bi = pbi[cur][P][slot];
#pragma unroll
            for (int off = 1; off < 4; off <<= 1) {
                float ov = __shfl_xor(bv, off);
                int   oi = __shfl_xor(bi, off);
                float os = __shfl_xor(sv, off);
                bool  take  = (ov > bv) || (ov == bv && oi < bi);
                float loser = take ? bv : ov;
                sv = fmaxf(fmaxf(sv, os), loser);
                if (take) { bv = ov; bi = oi; }
            }
            if (slot == 0) {
                int h   = hg * 8 + r;
                int pix = (((n * 64 + h) * 64) + P) * MM + m;
                out[pix] = bi;
                if (bv - sv < EPS) {
                    int s_ = atomicAdd(wl_cnt + m * 16, 1);   // per-m counters, 64B apart
                    if (s_ < WLC) wl[m * WLC + s_] = pix;
                }
            }
        }
        // no second barrier: next row writes lq[cur] only after ITS top (fenced by the
        // barrier above via next iteration's ordering) and partials go to buf cur^1.
    }
}

// ---- Kernel 4: fp64 rescue, 4 same-m pixels share one keffdT sweep ----
__global__ __launch_bounds__(256) void rescue_kernel(const float* __restrict__ latent,
                                                     const double* __restrict__ keffdT,
                                                     const int* __restrict__ wl_cnt,
                                                     const int* __restrict__ wl,
                                                     int* __restrict__ out) {
    __shared__ double sq[RPB][DM];       // 4 KB
    __shared__ double sval[256][RPB];    // 8 KB
    __shared__ int    sidx[256][RPB];    // 4 KB
    __shared__ int    spix[RPB];
    int b   = blockIdx.x;
    int m   = b & 3;
    int t   = threadIdx.x;
    int cnt = wl_cnt[m * 16];
    if (cnt > WLC) cnt = WLC;
    const int*    wlm = wl + m * WLC;
    const double* krm = keffdT + (size_t)m * DM * KC + t;   // column k=t

    for (int i0 = (b >> 2) * RPB; i0 < cnt; i0 += 256 * RPB) {
        // ---- load 4 pixels' q into LDS: 64 threads per pixel, 2 d's each ----
        int pi  = t >> 6;            // 0..3
        int dd  = (t & 63) * 2;      // 0..126
        int idx = i0 + pi;
        int vld = idx < cnt;
        int pix = wlm[vld ? idx : i0];
        int rem = pix >> 2;          // (n*64+h)*64 + w
        int w   = rem & 63;
        int bh  = rem >> 6;
        int n   = bh >> 6;
        int h   = bh & 63;
        const float* lp = latent + ((size_t)(n * 512 + m * DM)) * HW + h * WW_ + w;
        sq[pi][dd]     = (double)lp[(size_t)dd * HW];
        sq[pi][dd + 1] = (double)lp[(size_t)(dd + 1) * HW];
        if ((t & 63) == 0) spix[pi] = vld ? pix : -1;
        __syncthreads();

        // ---- one keffdT sweep, 4 dot products ----
        double s0 = 0.0, s1 = 0.0, s2 = 0.0, s3 = 0.0;
#pragma unroll 4
        for (int d = 0; d < DM; ++d) {
            double kd = krm[(size_t)d * KC];
            s0 = fma(sq[0][d], kd, s0);
            s1 = fma(sq[1][d], kd, s1);
            s2 = fma(sq[2][d], kd, s2);
            s3 = fma(sq[3][d], kd, s3);
        }
        sval[t][0] = s0; sval[t][1] = s1; sval[t][2] = s2; sval[t][3] = s3;
        sidx[t][0] = t;  sidx[t][1] = t;  sidx[t][2] = t;  sidx[t][3] = t;
        __syncthreads();

        // ---- combined tree reduction for all 4 pixels ----
        for (int stp = 128; stp > 0; stp >>= 1) {
            if (t < stp) {
#pragma unroll
                for (int p = 0; p < RPB; ++p) {
                    double vo = sval[t + stp][p], vm = sval[t][p];
                    int io = sidx[t + stp][p], im = sidx[t][p];
                    if (vo > vm || (vo == vm && io < im)) { sval[t][p] = vo; sidx[t][p] = io; }
                }
            }
            __syncthreads();
        }
        if (t < RPB) {
            int opix = spix[t];
            if (opix >= 0) out[opix] = sidx[0][t];
        }
        __syncthreads();
    }
}

extern "C" void kernel_launch(void* const* d_in, const int* in_sizes, int n_in,
                              void* d_out, int out_size, void* d_ws, size_t ws_size,
                              hipStream_t stream) {
    const float* latent = (const float*)d_in[0];   // [16,512,64,64]
    const float* cb     = (const float*)d_in[1];   // [4,256,128]
    const float* wq     = (const float*)d_in[2];   // [4,128,128]
    const float* wk     = (const float*)d_in[3];   // [4,128,128]
    int* out = (int*)d_out;                        // 262144 code indices (int32)

    // workspace layout (~2.1 MB)
    char* ws = (char*)d_ws;
    double*   A      = (double*)ws;     ws += (size_t)MM * DM * DM * sizeof(double);    // 512 KB
    double*   keffdT = (double*)ws;     ws += (size_t)MM * DM * KC * sizeof(double);    // 1 MB
    _Float16* keff16 = (_Float16*)ws;   ws += (size_t)MM * KC * DM * sizeof(_Float16);  // 256 KB
    int*      wl_cnt = (int*)ws;        ws += 256;                                      // 4 ctr, 64B apart
    int*      wl     = (int*)ws;        // 4 * WLC * 4 = 256 KB

    a_kernel<<<MM * DM, 128, 0, stream>>>(wk, wq, A, wl_cnt);
    keff_kernel<<<MM * KC, 128, 0, stream>>>(cb, A, keffdT, keff16);
    argmax_mfma<<<512, 512, 0, stream>>>(latent, keff16, out, wl_cnt, wl);
    rescue_kernel<<<1024, 256, 0, stream>>>(latent, keffdT, wl_cnt, wl, out);
}

// Round 10
// 250.473 us; speedup vs baseline: 1.1164x; 1.1164x over previous
//
#include <hip/hip_runtime.h>

// QuantizerEncoder: code[n,h,w,m] = argmax_k < wq[m] @ q_raw[n,h,w,m], wk[m] @ cb[m,k] >
// n=16, d=512, h=64, w=64, m=4, kcodes=256, dm=128
//
// Round 15: revert to the R12 champion (253.6us). R13 (depth-2 prefetch) was null;
// R14 (4x64-code wave split) spilled (Af=64 VGPRs pushes past the 128 unified cap of
// (512,4): VGPR_Count 64 + 32MB scratch WRITE, argmax 94us). Measured constraints:
// Af<=32 VGPRs in the 8-wave config; prefetch depth 1 is sufficient. Kept from R14:
// wl_cnt zeroing folded into a_kernel (memset dispatch dropped, ~2us).
// Structure: 512 blocks x 512 thr (8 waves x 32 codes), 8 rows/block, 1 barrier/row,
// double-buffered partials + parallel 8-way merge, amortized 4-pixel rescue.

#define MM   4
#define KC   256
#define DM   128
#define HW   4096   // h*w
#define WW_  64
#define EPS  0.045f
#define WLC  16384  // per-m worklist capacity
#define RPB  4      // pixels per rescue sweep
#define RSH  136    // LDS row stride in halfs (272B, 16B-aligned, conflict-free b128)

typedef _Float16 f16x8 __attribute__((ext_vector_type(8)));
typedef _Float16 f16x4 __attribute__((ext_vector_type(4)));
typedef _Float16 f16x2 __attribute__((ext_vector_type(2)));
typedef float    f32x4 __attribute__((ext_vector_type(4)));
typedef float    f32x2 __attribute__((ext_vector_type(2)));

// ---- Kernel 1: A[m][e][d] = sum_c wk[m][c][e] * wq[m][c][d]  (fp64); also zeroes wl_cnt ----
__global__ __launch_bounds__(128) void a_kernel(const float* __restrict__ wk,
                                                const float* __restrict__ wq,
                                                double* __restrict__ A,
                                                int* __restrict__ wl_cnt) {
    if (blockIdx.x == 0 && threadIdx.x < 64) wl_cnt[threadIdx.x] = 0;
    int me = blockIdx.x;           // m*128 + e
    int d  = threadIdx.x;
    int m  = me >> 7;
    int e  = me & 127;
    const float* wkm = wk + (size_t)m * DM * DM + e;       // wk[m][c][e], stride DM
    const float* wqm = wq + (size_t)m * DM * DM + d;       // wq[m][c][d], stride DM
    double s0 = 0.0, s1 = 0.0, s2 = 0.0, s3 = 0.0;
#pragma unroll 8
    for (int c = 0; c < DM; c += 4) {
        s0 = fma((double)wkm[(size_t)(c+0) * DM], (double)wqm[(size_t)(c+0) * DM], s0);
        s1 = fma((double)wkm[(size_t)(c+1) * DM], (double)wqm[(size_t)(c+1) * DM], s1);
        s2 = fma((double)wkm[(size_t)(c+2) * DM], (double)wqm[(size_t)(c+2) * DM], s2);
        s3 = fma((double)wkm[(size_t)(c+3) * DM], (double)wqm[(size_t)(c+3) * DM], s3);
    }
    A[(size_t)me * DM + d] = (s0 + s1) + (s2 + s3);
}

// ---- Kernel 2: keff[m][k][d] = sum_e cb[m][k][e]*A[m][e][d]; store fp16 + fp64-transposed ----
__global__ __launch_bounds__(128) void keff_kernel(const float* __restrict__ cb,
                                                   const double* __restrict__ A,
                                                   double* __restrict__ keffdT,
                                                   _Float16* __restrict__ keff16) {
    int mk = blockIdx.x;           // m*256 + k
    int d  = threadIdx.x;
    int m  = mk >> 8;
    int k  = mk & 255;
    const float*  cbr = cb + (size_t)mk * DM;              // cb[m][k][*]
    const double* Am  = A + (size_t)m * DM * DM + d;       // A[m][e][d], stride DM
    double s0 = 0.0, s1 = 0.0, s2 = 0.0, s3 = 0.0;
#pragma unroll 8
    for (int e = 0; e < DM; e += 4) {
        s0 = fma((double)cbr[e+0], Am[(size_t)(e+0) * DM], s0);
        s1 = fma((double)cbr[e+1], Am[(size_t)(e+1) * DM], s1);
        s2 = fma((double)cbr[e+2], Am[(size_t)(e+2) * DM], s2);
        s3 = fma((double)cbr[e+3], Am[(size_t)(e+3) * DM], s3);
    }
    double s = (s0 + s1) + (s2 + s3);
    keffdT[((size_t)m * DM + d) * KC + k] = s;             // transposed: rescue reads coalesced
    keff16[(size_t)mk * DM + d] = (_Float16)s;
}

// ---- Kernel 3: MFMA argmax, 8 waves x 32 codes, 8 rows/block, 512 blocks ----
__global__ __launch_bounds__(512, 4) void argmax_mfma(const float* __restrict__ latent,
                                                      const _Float16* __restrict__ keff16,
                                                      int* __restrict__ out,
                                                      int* __restrict__ wl_cnt,
                                                      int* __restrict__ wl) {
    __shared__ _Float16 lq[2][64 * RSH];   // 2 x 17,408 B q tiles
    __shared__ float pbv[2][64][8];        // double-buffered partials (merge overlaps next row)
    __shared__ float psv[2][64][8];
    __shared__ int   pbi[2][64][8];

    int blk  = blockIdx.x;          // 0..511 = n(16) x m(4) x hg(8)
    int n    = blk >> 5;
    int m    = (blk >> 3) & 3;
    int hg   = blk & 7;
    int tid  = threadIdx.x;
    int wave = tid >> 6;            // 0..7
    int lane = tid & 63;
    int col  = lane & 15;
    int quad = lane >> 4;
    int w2   = (tid & 31) * 2;      // staging: pixel base (2 pixels/thread)
    int db   = (tid >> 5) * 8;      // staging: d-plane base (16 groups x 8 = 128)

    // ---- A-frags: this wave's 32 codes [wave*32, wave*32+32), 32 VGPRs ----
    f16x8 Af[2][4];
    {
        const _Float16* kbase = keff16 + ((size_t)m * KC + wave * 32) * DM;
#pragma unroll
        for (int t = 0; t < 2; ++t)
#pragma unroll
            for (int s = 0; s < 4; ++s)
                Af[t][s] = *(const f16x8*)(kbase + (size_t)(t * 16 + col) * DM + s * 32 + quad * 8);
    }

    const float* lp0 = latent + ((size_t)(n * 512 + m * DM)) * HW + (size_t)(hg * 8) * WW_;

    // ---- stage row 0: 8 planes x 2 pixels per thread, register-transpose, 2x ds_write_b128 ----
    {
        f32x2 pf[8];
#pragma unroll
        for (int pp = 0; pp < 8; ++pp)
            pf[pp] = *(const f32x2*)(lp0 + (size_t)(db + pp) * HW + w2);
#pragma unroll
        for (int j = 0; j < 2; ++j) {
            f16x8 v;
#pragma unroll
            for (int pp = 0; pp < 8; ++pp) v[pp] = (_Float16)pf[pp][j];
            *(f16x8*)&lq[0][(size_t)(w2 + j) * RSH + db] = v;
        }
    }
    __syncthreads();

    for (int r = 0; r < 8; ++r) {
        int cur = r & 1;

        // ---- prefetch next row: raw float2 regs, convert LATER ----
        f32x2 pf[8];
        if (r < 7) {
            const float* lp = lp0 + (size_t)(r + 1) * WW_;
#pragma unroll
            for (int pp = 0; pp < 8; ++pp)
                pf[pp] = *(const f32x2*)(lp + (size_t)(db + pp) * HW + w2);
        }

        // ---- compute + scan per pixel-tile p; write partials to buf=cur ----
#pragma unroll
        for (int p = 0; p < 4; ++p) {
            f16x8 Bf[4];
#pragma unroll
            for (int s = 0; s < 4; ++s)
                Bf[s] = *(const f16x8*)&lq[cur][(size_t)(p * 16 + col) * RSH + s * 32 + quad * 8];
            f32x4 acc[2];
#pragma unroll
            for (int t = 0; t < 2; ++t) {
                f32x4 c = (f32x4){0.f, 0.f, 0.f, 0.f};
                c = __builtin_amdgcn_mfma_f32_16x16x32_f16(Af[t][0], Bf[0], c, 0, 0, 0);
                c = __builtin_amdgcn_mfma_f32_16x16x32_f16(Af[t][1], Bf[1], c, 0, 0, 0);
                c = __builtin_amdgcn_mfma_f32_16x16x32_f16(Af[t][2], Bf[2], c, 0, 0, 0);
                c = __builtin_amdgcn_mfma_f32_16x16x32_f16(Af[t][3], Bf[3], c, 0, 0, 0);
                acc[t] = c;
            }
            // C col=pixel-in-tile, row=quad*4+reg=code-in-tile
            float bv = acc[0][0];
            int   bi = wave * 32 + quad * 4;
            float sv = -3.0e38f;
#pragma unroll
            for (int t = 0; t < 2; ++t)
#pragma unroll
                for (int g = 0; g < 4; ++g) {
                    if (t == 0 && g == 0) continue;
                    float v   = acc[t][g];
                    int   idx = wave * 32 + t * 16 + quad * 4 + g;   // ascending scan
                    if (v > bv)      { sv = bv; bv = v; bi = idx; }
                    else if (v > sv) sv = v;
                }
            // merge across the 4 quads holding this pixel
#pragma unroll
            for (int off = 16; off < 64; off <<= 1) {
                float ov = __shfl_xor(bv, off);
                int   oi = __shfl_xor(bi, off);
                float os = __shfl_xor(sv, off);
                bool  take  = (ov > bv) || (ov == bv && oi < bi);
                float loser = take ? bv : ov;
                sv = fmaxf(fmaxf(sv, os), loser);
                if (take) { bv = ov; bi = oi; }
            }
            if (quad == 0) {
                int P = p * 16 + col;
                pbv[cur][P][wave] = bv; psv[cur][P][wave] = sv; pbi[cur][P][wave] = bi;
            }
        }

        // ---- deferred staging BEFORE the barrier (writes lq[cur^1], no reader yet) ----
        if (r < 7) {
#pragma unroll
            for (int j = 0; j < 2; ++j) {
                f16x8 v;
#pragma unroll
                for (int pp = 0; pp < 8; ++pp) v[pp] = (_Float16)pf[pp][j];
                *(f16x8*)&lq[cur ^ 1][(size_t)(w2 + j) * RSH + db] = v;
            }
        }
        __syncthreads();   // ONE barrier per row: partials[cur] + lq[cur^1] both published

        // ---- parallel 8-way merge: 512 threads, pixel P=tid>>3, slot=tid&7 ----
        {
            int P    = tid >> 3;
            int slot = tid & 7;
            float bv = pbv[cur][P][slot];
            float sv = psv[cur][P][slot];
            int   bi = pbi[cur][P][slot];
#pragma unroll
            for (int off = 1; off < 8; off <<= 1) {
                float ov = __shfl_xor(bv, off);
                int   oi = __shfl_xor(bi, off);
                float os = __shfl_xor(sv, off);
                bool  take  = (ov > bv) || (ov == bv && oi < bi);
                float loser = take ? bv : ov;
                sv = fmaxf(fmaxf(sv, os), loser);
                if (take) { bv = ov; bi = oi; }
            }
            if (slot == 0) {
                int h   = hg * 8 + r;
                int pix = (((n * 64 + h) * 64) + P) * MM + m;
                out[pix] = bi;
                if (bv - sv < EPS) {
                    int s_ = atomicAdd(wl_cnt + m * 16, 1);   // per-m counters, 64B apart
                    if (s_ < WLC) wl[m * WLC + s_] = pix;
                }
            }
        }
        // no second barrier: next row writes pbv[cur^1] (other buffer); pbv[cur] is
        // reused only at r+2, after the next row's barrier fences all merges.
    }
}

// ---- Kernel 4: fp64 rescue, 4 same-m pixels share one keffdT sweep ----
// Thread owns column k=t; 128 coalesced loads of keffdT[m][d][t]; 4 FMA chains
// amortize each load (L2 traffic /4 vs per-pixel sweep).
__global__ __launch_bounds__(256) void rescue_kernel(const float* __restrict__ latent,
                                                     const double* __restrict__ keffdT,
                                                     const int* __restrict__ wl_cnt,
                                                     const int* __restrict__ wl,
                                                     int* __restrict__ out) {
    __shared__ double sq[RPB][DM];       // 4 KB
    __shared__ double sval[256][RPB];    // 8 KB
    __shared__ int    sidx[256][RPB];    // 4 KB
    __shared__ int    spix[RPB];
    int b   = blockIdx.x;
    int m   = b & 3;
    int t   = threadIdx.x;
    int cnt = wl_cnt[m * 16];
    if (cnt > WLC) cnt = WLC;
    const int*    wlm = wl + m * WLC;
    const double* krm = keffdT + (size_t)m * DM * KC + t;   // column k=t

    for (int i0 = (b >> 2) * RPB; i0 < cnt; i0 += 256 * RPB) {
        // ---- load 4 pixels' q into LDS: 64 threads per pixel, 2 d's each ----
        int pi  = t >> 6;            // 0..3
        int dd  = (t & 63) * 2;      // 0..126
        int idx = i0 + pi;
        int vld = idx < cnt;
        int pix = wlm[vld ? idx : i0];
        int rem = pix >> 2;          // (n*64+h)*64 + w
        int w   = rem & 63;
        int bh  = rem >> 6;
        int n   = bh >> 6;
        int h   = bh & 63;
        const float* lp = latent + ((size_t)(n * 512 + m * DM)) * HW + h * WW_ + w;
        sq[pi][dd]     = (double)lp[(size_t)dd * HW];
        sq[pi][dd + 1] = (double)lp[(size_t)(dd + 1) * HW];
        if ((t & 63) == 0) spix[pi] = vld ? pix : -1;
        __syncthreads();

        // ---- one keffdT sweep, 4 dot products ----
        double s0 = 0.0, s1 = 0.0, s2 = 0.0, s3 = 0.0;
#pragma unroll 4
        for (int d = 0; d < DM; ++d) {
            double kd = krm[(size_t)d * KC];
            s0 = fma(sq[0][d], kd, s0);
            s1 = fma(sq[1][d], kd, s1);
            s2 = fma(sq[2][d], kd, s2);
            s3 = fma(sq[3][d], kd, s3);
        }
        sval[t][0] = s0; sval[t][1] = s1; sval[t][2] = s2; sval[t][3] = s3;
        sidx[t][0] = t;  sidx[t][1] = t;  sidx[t][2] = t;  sidx[t][3] = t;
        __syncthreads();

        // ---- combined tree reduction for all 4 pixels ----
        for (int stp = 128; stp > 0; stp >>= 1) {
            if (t < stp) {
#pragma unroll
                for (int p = 0; p < RPB; ++p) {
                    double vo = sval[t + stp][p], vm = sval[t][p];
                    int io = sidx[t + stp][p], im = sidx[t][p];
                    if (vo > vm || (vo == vm && io < im)) { sval[t][p] = vo; sidx[t][p] = io; }
                }
            }
            __syncthreads();
        }
        if (t < RPB) {
            int opix = spix[t];
            if (opix >= 0) out[opix] = sidx[0][t];
        }
        __syncthreads();
    }
}

extern "C" void kernel_launch(void* const* d_in, const int* in_sizes, int n_in,
                              void* d_out, int out_size, void* d_ws, size_t ws_size,
                              hipStream_t stream) {
    const float* latent = (const float*)d_in[0];   // [16,512,64,64]
    const float* cb     = (const float*)d_in[1];   // [4,256,128]
    const float* wq     = (const float*)d_in[2];   // [4,128,128]
    const float* wk     = (const float*)d_in[3];   // [4,128,128]
    int* out = (int*)d_out;                        // 262144 code indices (int32)

    // workspace layout (~2.1 MB)
    char* ws = (char*)d_ws;
    double*   A      = (double*)ws;     ws += (size_t)MM * DM * DM * sizeof(double);    // 512 KB
    double*   keffdT = (double*)ws;     ws += (size_t)MM * DM * KC * sizeof(double);    // 1 MB
    _Float16* keff16 = (_Float16*)ws;   ws += (size_t)MM * KC * DM * sizeof(_Float16);  // 256 KB
    int*      wl_cnt = (int*)ws;        ws += 256;                                      // 4 ctr, 64B apart
    int*      wl     = (int*)ws;        // 4 * WLC * 4 = 256 KB

    a_kernel<<<MM * DM, 128, 0, stream>>>(wk, wq, A, wl_cnt);
    keff_kernel<<<MM * KC, 128, 0, stream>>>(cb, A, keffdT, keff16);
    argmax_mfma<<<512, 512, 0, stream>>>(latent, keff16, out, wl_cnt, wl);
    rescue_kernel<<<1024, 256, 0, stream>>>(latent, keffdT, wl_cnt, wl, out);
}